// Round 11
// baseline (274.769 us; speedup 1.0000x reference)
//
#include <hip/hip_runtime.h>
#include <hip/hip_bf16.h>

using bf16 = __hip_bfloat16;
using bf16x8 = __attribute__((ext_vector_type(8))) __bf16;
using f32x4 = __attribute__((ext_vector_type(4))) float;

typedef const __attribute__((address_space(1))) void* gas_ptr;
typedef __attribute__((address_space(3))) void* las_ptr;
#define LOAD_LDS16(g, l) \
    __builtin_amdgcn_global_load_lds((gas_ptr)(const void*)(g), (las_ptr)(void*)(l), 16, 0, 0)

#define LOG_DIM 11
#define BDIM 2048
#define NFEAT 2048
#define BATCH 16384

// ---------------------------------------------------------------------------
// prep1: butterfly_wout [0,2048) || transpose_cvt [2048,6144)
// ---------------------------------------------------------------------------
__global__ __launch_bounds__(256) void prep1(const float* __restrict__ w_out,
                                             const float* __restrict__ a_pad,
                                             const float* __restrict__ b_pad,
                                             const float* __restrict__ w_in,
                                             bf16* __restrict__ woutb,
                                             bf16* __restrict__ wint) {
    __shared__ float v[BDIM];
    __shared__ float tile[32][33];
    const int t = threadIdx.x;
    if (blockIdx.x < 2048) {
        const int o = blockIdx.x;
        const float* row = w_out + (size_t)o * BDIM;
        for (int i = t; i < BDIM / 4; i += 256)
            ((float4*)v)[i] = ((const float4*)row)[i];
        __syncthreads();
        for (int l = LOG_DIM - 1; l >= 0; --l) {
            #pragma unroll
            for (int pp = 0; pp < 4; ++pp) {
                int p = t + pp * 256;
                int j = p >> l;
                int s = p & ((1 << l) - 1);
                int i0 = (j << (l + 1)) | s;
                int i1 = i0 + (1 << l);
                float a = a_pad[l * (BDIM / 2) + j];
                float b = b_pad[l * (BDIM / 2) + j];
                float x0 = v[i0], x1 = v[i1];
                v[i0] = a * x0 - b * x1;
                v[i1] = b * x0 + a * x1;
            }
            __syncthreads();
        }
        union { bf16 h[8]; int4 vv; } u;
        #pragma unroll
        for (int j = 0; j < 8; ++j) u.h[j] = __float2bfloat16(v[t * 8 + j]);
        *(int4*)(woutb + (size_t)o * BDIM + t * 8) = u.vv;
    } else {
        const int b = blockIdx.x - 2048;
        const int bx = b & 63, by = b >> 6;
        const int tx = t & 31, ty = t >> 5;
        #pragma unroll
        for (int r = ty; r < 32; r += 8)
            tile[r][tx] = w_in[(size_t)(by * 32 + r) * NFEAT + bx * 32 + tx];
        __syncthreads();
        #pragma unroll
        for (int r = ty; r < 32; r += 8)
            wint[(size_t)(bx * 32 + r) * NFEAT + by * 32 + tx] = __float2bfloat16(tile[tx][r]);
    }
}

// ---------------------------------------------------------------------------
// gemmM_sk: M = WoutB @ W_in^T-layout, 8-phase 256² structure, splitK=4.
//   Grid (8,8,4) = 256 blocks = 1/CU.  (r10, unchanged)
// ---------------------------------------------------------------------------
#define GK 2048
#define LDS_SLOT 65536
#define LDS_BOFF 32768
#define LDS_KH 16384

__global__ __launch_bounds__(512, 2) void gemmM_sk(const bf16* __restrict__ A,
                                                   const bf16* __restrict__ Bt,
                                                   bf16* __restrict__ part) {
    __shared__ __align__(16) char lds[131072];

    const int tid = threadIdx.x;
    const int wave = tid >> 6, lane = tid & 63;
    const int l15 = lane & 15, kc = lane >> 4;
    const int wm = wave >> 2, wn = wave & 3;

    const int mBase = blockIdx.y * 256, nBase = blockIdx.x * 256;
    const int kz = blockIdx.z;
    bf16* C = part + (size_t)kz * GK * GK;

    const int c_log = tid ^ ((tid >> 3) & 3);
    const int srow = c_log >> 2, skc = c_log & 3;
    const bf16* gA = A + (size_t)(mBase + srow) * GK + kz * 512 + skc * 8;
    const bf16* gB = Bt + (size_t)(nBase + srow) * GK + kz * 512 + skc * 8;
    const int stgBase = wave * 1024;

    const int kcx = kc ^ ((l15 >> 1) & 3);
    const int aoff = wm * 8192 + l15 * 64 + kcx * 16;
    const int boff = LDS_BOFF + wn * 4096 + l15 * 64 + kcx * 16;

    f32x4 acc[8][4];
    #pragma unroll
    for (int i = 0; i < 8; ++i)
        #pragma unroll
        for (int j = 0; j < 4; ++j) acc[i][j] = (f32x4){0.f, 0.f, 0.f, 0.f};

    bf16x8 Af[4], Bf[4];

#define STG(GSRC, LDSC, KT, KH) do {                                        \
    const bf16* _g = (GSRC) + (KT) * 64 + (KH) * 32;                        \
    LOAD_LDS16(_g, lds + (LDSC) + stgBase);                                 \
    LOAD_LDS16(_g + (size_t)128 * GK, lds + (LDSC) + stgBase + 8192);       \
} while (0)

#define READP(SLOT, KH, MH, DOB) do {                                       \
    const int _rb = (SLOT) * LDS_SLOT + (KH) * LDS_KH;                      \
    _Pragma("unroll")                                                       \
    for (int _f = 0; _f < 4; ++_f)                                          \
        Af[_f] = *(const bf16x8*)(lds + _rb + aoff + (MH) * 4096 + _f * 1024); \
    if (DOB) {                                                              \
        _Pragma("unroll")                                                   \
        for (int _f = 0; _f < 4; ++_f)                                      \
            Bf[_f] = *(const bf16x8*)(lds + _rb + boff + _f * 1024);        \
    }                                                                       \
} while (0)

    STG(gA, 0 * LDS_SLOT + 0, 0, 0);
    STG(gB, 0 * LDS_SLOT + LDS_BOFF + 0, 0, 0);
    STG(gA, 0 * LDS_SLOT + LDS_KH, 0, 1);
    STG(gB, 0 * LDS_SLOT + LDS_BOFF + LDS_KH, 0, 1);
    STG(gA, 1 * LDS_SLOT + 0, 1, 0);
    STG(gB, 1 * LDS_SLOT + LDS_BOFF + 0, 1, 0);
    STG(gB, 1 * LDS_SLOT + LDS_BOFF + LDS_KH, 1, 1);
    asm volatile("s_waitcnt vmcnt(6)");
    __builtin_amdgcn_s_barrier();

#define PH(S, KH, MH, DOB, SGSRC, SLDS, SKT, SKH, DOVM) do {                \
    READP(S, KH, MH, DOB);                                                  \
    STG(SGSRC, SLDS, SKT, SKH);                                             \
    if (DOVM) asm volatile("s_waitcnt vmcnt(6)");                           \
    __builtin_amdgcn_sched_barrier(0);                                      \
    __builtin_amdgcn_s_barrier();                                           \
    asm volatile("s_waitcnt lgkmcnt(0)");                                   \
    __builtin_amdgcn_sched_barrier(0);                                      \
    __builtin_amdgcn_s_setprio(1);                                          \
    _Pragma("unroll")                                                       \
    for (int _mf = 0; _mf < 4; ++_mf)                                       \
        _Pragma("unroll")                                                   \
        for (int _nf = 0; _nf < 4; ++_nf)                                   \
            acc[(MH) * 4 + _mf][_nf] = __builtin_amdgcn_mfma_f32_16x16x32_bf16( \
                Af[_mf], Bf[_nf], acc[(MH) * 4 + _mf][_nf], 0, 0, 0);       \
    __builtin_amdgcn_s_setprio(0);                                          \
    __builtin_amdgcn_s_barrier();                                           \
} while (0)

    for (int it = 0; it < 4; ++it) {
        const int t0 = 2 * it;
        const int t1 = (t0 + 1) & 7, t2 = (t0 + 2) & 7, t3 = (t0 + 3) & 7;
        PH(0, 0, 0, 1, gA, 1 * LDS_SLOT + LDS_KH,            t1, 1, 0);
        PH(0, 0, 1, 0, gB, 0 * LDS_SLOT + LDS_BOFF,          t2, 0, 0);
        PH(0, 1, 0, 1, gA, 0 * LDS_SLOT + 0,                 t2, 0, 0);
        PH(0, 1, 1, 0, gB, 0 * LDS_SLOT + LDS_BOFF + LDS_KH, t2, 1, 1);
        PH(1, 0, 0, 1, gA, 0 * LDS_SLOT + LDS_KH,            t2, 1, 0);
        PH(1, 0, 1, 0, gB, 1 * LDS_SLOT + LDS_BOFF,          t3, 0, 0);
        PH(1, 1, 0, 1, gA, 1 * LDS_SLOT + 0,                 t3, 0, 0);
        PH(1, 1, 1, 0, gB, 1 * LDS_SLOT + LDS_BOFF + LDS_KH, t3, 1, 1);
    }

    const int cRow0 = mBase + wm * 128 + (lane >> 4) * 4;
    const int cCol0 = nBase + wn * 64 + l15;
    #pragma unroll
    for (int Mf = 0; Mf < 8; ++Mf)
        #pragma unroll
        for (int nf = 0; nf < 4; ++nf)
            #pragma unroll
            for (int r = 0; r < 4; ++r)
                C[(size_t)(cRow0 + Mf * 16 + r) * GK + cCol0 + nf * 16] =
                    __float2bfloat16(acc[Mf][nf][r]);
#undef PH
#undef READP
#undef STG
}

// ---------------------------------------------------------------------------
// add four bf16 partials -> bf16
// ---------------------------------------------------------------------------
__global__ __launch_bounds__(256) void addcvt4(const bf16* __restrict__ p,
                                               bf16* __restrict__ out) {
    size_t i = ((size_t)blockIdx.x * 256 + threadIdx.x) * 8;
    constexpr size_t STRIDE = (size_t)2048 * 2048;
    float s[8];
    #pragma unroll
    for (int j = 0; j < 8; ++j) s[j] = 0.f;
    #pragma unroll
    for (int z = 0; z < 4; ++z) {
        union { bf16 h[8]; int4 v; } a;
        a.v = *(const int4*)(p + z * STRIDE + i);
        #pragma unroll
        for (int j = 0; j < 8; ++j) s[j] += __bfloat162float(a.h[j]);
    }
    union { bf16 h[8]; int4 v; } o;
    #pragma unroll
    for (int j = 0; j < 8; ++j) o.h[j] = __float2bfloat16(s[j]);
    *(int4*)(out + i) = o.v;
}

// ---------------------------------------------------------------------------
// Main GEMM v4: A staged DIRECTLY from fp32 x (no x_bf pre-pass).
//   8-phase r9 schedule; B via gload_lds (unchanged); A via reg-staging:
//   A-phase p issues 4x global_load_dwordx4 (fp32) for the region written
//   at p+2, converts the p-2-issued regs to bf16, 2x ds_write_b128 into the
//   SAME linear LDS layout (pre-swizzled source => READP unchanged).
//   Ledger: compiler guards A-reg use (plain C loads); any wait retiring
//   A4(p-2) retires all older B-gloads (vmcnt ordered) => B regions retire
//   >=4 phases + bar1 before their read at +7.  ds_write visibility via the
//   existing lgkmcnt(0)+barrier chain.  Write-after-read safe: writer is
//   past bar2 of the region's last reading phase.  Ra/Rb named alternation.
// ---------------------------------------------------------------------------
__global__ __launch_bounds__(512, 2) void gemm256(const float* __restrict__ X,
                                                  const bf16* __restrict__ Bt,
                                                  const float* __restrict__ bias,
                                                  float* __restrict__ C) {
    __shared__ __align__(16) char lds[131072];

    const int tid = threadIdx.x;
    const int wave = tid >> 6, lane = tid & 63;
    const int l15 = lane & 15, kc = lane >> 4;
    const int wm = wave >> 2, wn = wave & 3;

    const int bid = blockIdx.x;
    const int swz = (bid & 7) * 64 + (bid >> 3);
    const int bm = swz >> 3, bn = swz & 7;
    const int mBase = bm * 256, nBase = bn * 256;

    // pre-swizzled source mapping (identical logical layout to bf16 path)
    const int c_log = tid ^ ((tid >> 3) & 3);
    const int srow = c_log >> 2, skc = c_log & 3;
    const float* xA = X + (size_t)(mBase + srow) * GK + skc * 8;
    const bf16* gB = Bt + (size_t)(nBase + srow) * GK + skc * 8;
    const int stgBase = wave * 1024;
    const int sOff = tid * 16;          // explicit ds_write dest (== gload_lds dest)

    const int kcx = kc ^ ((l15 >> 1) & 3);
    const int aoff = wm * 8192 + l15 * 64 + kcx * 16;
    const int boff = LDS_BOFF + wn * 4096 + l15 * 64 + kcx * 16;

    f32x4 acc[8][4];
    #pragma unroll
    for (int i = 0; i < 8; ++i)
        #pragma unroll
        for (int j = 0; j < 4; ++j) acc[i][j] = (f32x4){0.f, 0.f, 0.f, 0.f};

    bf16x8 Af[4], Bf[4];
    float4 Ra0, Ra1, Ra2, Ra3, Rb0, Rb1, Rb2, Rb3;

#define STGB(LDSC, KT, KH) do {                                             \
    const bf16* _g = gB + (KT) * 64 + (KH) * 32;                            \
    LOAD_LDS16(_g, lds + (LDSC) + stgBase);                                 \
    LOAD_LDS16(_g + (size_t)128 * GK, lds + (LDSC) + stgBase + 8192);       \
} while (0)

#define AISSUE(R0, R1, R2, R3, KT, KH) do {                                 \
    const float* _g = xA + (KT) * 64 + (KH) * 32;                           \
    R0 = *(const float4*)(_g);                                              \
    R1 = *(const float4*)(_g + 4);                                          \
    R2 = *(const float4*)(_g + (size_t)128 * GK);                           \
    R3 = *(const float4*)(_g + (size_t)128 * GK + 4);                       \
} while (0)

#define AWRITE(R0, R1, R2, R3, WLDSC) do {                                  \
    union { bf16 h[8]; int4 v; } _u0, _u1;                                  \
    _u0.h[0] = __float2bfloat16(R0.x); _u0.h[1] = __float2bfloat16(R0.y);   \
    _u0.h[2] = __float2bfloat16(R0.z); _u0.h[3] = __float2bfloat16(R0.w);   \
    _u0.h[4] = __float2bfloat16(R1.x); _u0.h[5] = __float2bfloat16(R1.y);   \
    _u0.h[6] = __float2bfloat16(R1.z); _u0.h[7] = __float2bfloat16(R1.w);   \
    _u1.h[0] = __float2bfloat16(R2.x); _u1.h[1] = __float2bfloat16(R2.y);   \
    _u1.h[2] = __float2bfloat16(R2.z); _u1.h[3] = __float2bfloat16(R2.w);   \
    _u1.h[4] = __float2bfloat16(R3.x); _u1.h[5] = __float2bfloat16(R3.y);   \
    _u1.h[6] = __float2bfloat16(R3.z); _u1.h[7] = __float2bfloat16(R3.w);   \
    *(int4*)(lds + (WLDSC) + sOff) = _u0.v;                                 \
    *(int4*)(lds + (WLDSC) + sOff + 8192) = _u1.v;                          \
} while (0)

#define READP(SLOT, KH, MH, DOB) do {                                       \
    const int _rb = (SLOT) * LDS_SLOT + (KH) * LDS_KH;                      \
    _Pragma("unroll")                                                       \
    for (int _f = 0; _f < 4; ++_f)                                          \
        Af[_f] = *(const bf16x8*)(lds + _rb + aoff + (MH) * 4096 + _f * 1024); \
    if (DOB) {                                                              \
        _Pragma("unroll")                                                   \
        for (int _f = 0; _f < 4; ++_f)                                      \
            Bf[_f] = *(const bf16x8*)(lds + _rb + boff + _f * 1024);        \
    }                                                                       \
} while (0)

#define MFMAS(MH)                                                           \
    __builtin_amdgcn_s_setprio(1);                                          \
    _Pragma("unroll")                                                       \
    for (int _mf = 0; _mf < 4; ++_mf)                                       \
        _Pragma("unroll")                                                   \
        for (int _nf = 0; _nf < 4; ++_nf)                                   \
            acc[(MH) * 4 + _mf][_nf] = __builtin_amdgcn_mfma_f32_16x16x32_bf16( \
                Af[_mf], Bf[_nf], acc[(MH) * 4 + _mf][_nf], 0, 0, 0);       \
    __builtin_amdgcn_s_setprio(0);

    // A-phase: issue next A-region loads, convert+write the p-2 regs,
    // read this phase's frags, sync, MFMA.
#define APH(S, KH, MH, W0, W1, W2, W3, WLDSC, I0, I1, I2, I3, IKT, IKH) do {\
    AISSUE(I0, I1, I2, I3, IKT, IKH);                                       \
    __builtin_amdgcn_sched_barrier(0);                                      \
    asm volatile("s_waitcnt vmcnt(6)");                                     \
    AWRITE(W0, W1, W2, W3, WLDSC);                                          \
    READP(S, KH, MH, 1);                                                    \
    __builtin_amdgcn_sched_barrier(0);                                      \
    __builtin_amdgcn_s_barrier();                                           \
    asm volatile("s_waitcnt lgkmcnt(0)");                                   \
    __builtin_amdgcn_sched_barrier(0);                                      \
    MFMAS(MH)                                                               \
    __builtin_amdgcn_s_barrier();                                           \
} while (0)

    // B-phase: stage one B region (gload_lds), read A frags, sync, MFMA.
#define BPH(S, KH, MH, BLDSC, BKT, BKH) do {                                \
    READP(S, KH, MH, 0);                                                    \
    STGB(BLDSC, BKT, BKH);                                                  \
    __builtin_amdgcn_sched_barrier(0);                                      \
    __builtin_amdgcn_s_barrier();                                           \
    asm volatile("s_waitcnt lgkmcnt(0)");                                   \
    __builtin_amdgcn_sched_barrier(0);                                      \
    MFMAS(MH)                                                               \
    __builtin_amdgcn_s_barrier();                                           \
} while (0)

    // ---- prologue ----
    STGB(0 * LDS_SLOT + LDS_BOFF + 0, 0, 0);        // S0B0 <- t0
    STGB(0 * LDS_SLOT + LDS_BOFF + LDS_KH, 0, 1);   // S0B1 <- t0
    STGB(1 * LDS_SLOT + LDS_BOFF + 0, 1, 0);        // S1B0 <- t1
    STGB(1 * LDS_SLOT + LDS_BOFF + LDS_KH, 1, 1);   // S1B1 <- t1
    AISSUE(Ra0, Ra1, Ra2, Ra3, 0, 0);
    AWRITE(Ra0, Ra1, Ra2, Ra3, 0 * LDS_SLOT + 0);            // S0A0
    AISSUE(Ra0, Ra1, Ra2, Ra3, 0, 1);
    AWRITE(Ra0, Ra1, Ra2, Ra3, 0 * LDS_SLOT + LDS_KH);       // S0A1
    AISSUE(Ra0, Ra1, Ra2, Ra3, 1, 0);
    AWRITE(Ra0, Ra1, Ra2, Ra3, 1 * LDS_SLOT + 0);            // S1A0
    AISSUE(Ra0, Ra1, Ra2, Ra3, 1, 1);                        // regs for P0 (S1A1)
    asm volatile("s_waitcnt lgkmcnt(0)");
    __builtin_amdgcn_sched_barrier(0);
    __builtin_amdgcn_s_barrier();

    // ---- main loop: 32 K-tiles, 2/iter ----
    // A map: P0 writes S1A1<-(t1,1)[regs from prev P6]; P2 S0A0<-(t2,0);
    //        P4 S0A1<-(t2,1); P6 S1A0<-(t3,0); issues: P0->(t2,0), P2->(t2,1),
    //        P4->(t3,0), P6->(t3,1)=next-P0's (t1',1).
    // B map (= r9): P1 S0B0<-(t2,0); P3 S0B1<-(t2,1); P5 S1B0<-(t3,0);
    //        P7 S1B1<-(t3,1).
    for (int it = 0; it < 16; ++it) {
        const int t0 = 2 * it;
        const int t1 = (t0 + 1) & 31, t2 = (t0 + 2) & 31, t3 = (t0 + 3) & 31;
        (void)t1;
        APH(0, 0, 0, Ra0, Ra1, Ra2, Ra3, 1 * LDS_SLOT + LDS_KH,
                     Rb0, Rb1, Rb2, Rb3, t2, 0);
        BPH(0, 0, 1, 0 * LDS_SLOT + LDS_BOFF, t2, 0);
        APH(0, 1, 0, Rb0, Rb1, Rb2, Rb3, 0 * LDS_SLOT + 0,
                     Ra0, Ra1, Ra2, Ra3, t2, 1);
        BPH(0, 1, 1, 0 * LDS_SLOT + LDS_BOFF + LDS_KH, t2, 1);
        APH(1, 0, 0, Ra0, Ra1, Ra2, Ra3, 0 * LDS_SLOT + LDS_KH,
                     Rb0, Rb1, Rb2, Rb3, t3, 0);
        BPH(1, 0, 1, 1 * LDS_SLOT + LDS_BOFF, t3, 0);
        APH(1, 1, 0, Rb0, Rb1, Rb2, Rb3, 1 * LDS_SLOT + 0,
                     Ra0, Ra1, Ra2, Ra3, t3, 1);
        BPH(1, 1, 1, 1 * LDS_SLOT + LDS_BOFF + LDS_KH, t3, 1);
    }

    // epilogue: C/D layout col=lane&15, row=(lane>>4)*4+reg (m89-verified)
    const int cRow0 = mBase + wm * 128 + (lane >> 4) * 4;
    const int cCol0 = nBase + wn * 64 + l15;
    float bv[4];
    #pragma unroll
    for (int nf = 0; nf < 4; ++nf) bv[nf] = bias[cCol0 + nf * 16];
    #pragma unroll
    for (int Mf = 0; Mf < 8; ++Mf)
        #pragma unroll
        for (int nf = 0; nf < 4; ++nf)
            #pragma unroll
            for (int r = 0; r < 4; ++r)
                C[(size_t)(cRow0 + Mf * 16 + r) * GK + cCol0 + nf * 16] =
                    acc[Mf][nf][r] + bv[nf];
#undef APH
#undef BPH
#undef MFMAS
#undef READP
#undef AWRITE
#undef AISSUE
#undef STGB
}

// ---------------------------------------------------------------------------
// launch
// ---------------------------------------------------------------------------
extern "C" void kernel_launch(void* const* d_in, const int* in_sizes, int n_in,
                              void* d_out, int out_size, void* d_ws, size_t ws_size,
                              hipStream_t stream) {
    const float* x     = (const float*)d_in[0];
    const float* w_in  = (const float*)d_in[1];
    const float* w_out = (const float*)d_in[2];
    const float* b_out = (const float*)d_in[3];
    const float* a_pad = (const float*)d_in[4];
    const float* b_pad = (const float*)d_in[5];
    float* out = (float*)d_out;

    char* ws = (char*)d_ws;
    bf16* woutb = (bf16*)ws;                        // 8,388,608 B
    bf16* wint  = (bf16*)(ws + (size_t)8388608);    // 8,388,608 B
    bf16* mcomb = (bf16*)(ws + (size_t)16777216);   // 8,388,608 B (ws total 25 MB)

    // split-K partials live in d_out (134 MB, fully overwritten by gemm256)
    bf16* part = (bf16*)d_out;                      // 4 x 8 MB

    // prep1: butterfly(W_out) || transpose(W_in)   (x-cvt eliminated)
    prep1<<<dim3(6144), dim3(256), 0, stream>>>(w_out, a_pad, b_pad, w_in,
                                                woutb, wint);
    // M = (W_out·B) @ W_in: 8-phase 256² structure, splitK=4, 1 blk/CU
    gemmM_sk<<<dim3(8, 8, 4), dim3(512), 0, stream>>>(woutb, wint, part);
    addcvt4<<<dim3(NFEAT * BDIM / (256 * 8)), dim3(256), 0, stream>>>(part, mcomb);
    // out = x @ M^T + b  (A staged directly from fp32 x)
    gemm256<<<dim3((BATCH / 256) * (NFEAT / 256)), dim3(512), 0, stream>>>(
        x, mcomb, b_out, out);
}

// Round 12
// 227.229 us; speedup vs baseline: 1.2092x; 1.2092x over previous
//
#include <hip/hip_runtime.h>
#include <hip/hip_bf16.h>

using bf16 = __hip_bfloat16;
using bf16x8 = __attribute__((ext_vector_type(8))) __bf16;
using f32x4 = __attribute__((ext_vector_type(4))) float;

typedef const __attribute__((address_space(1))) void* gas_ptr;
typedef __attribute__((address_space(3))) void* las_ptr;
#define LOAD_LDS16(g, l) \
    __builtin_amdgcn_global_load_lds((gas_ptr)(const void*)(g), (las_ptr)(void*)(l), 16, 0, 0)

#define LOG_DIM 11
#define BDIM 2048
#define NFEAT 2048
#define BATCH 16384

__device__ __forceinline__ void cvt_chunk(const float* __restrict__ x,
                                          bf16* __restrict__ x_bf, int chunk, int tid) {
    // one chunk = 16 rows x 2048 fp32 -> bf16
    #pragma unroll
    for (int it = 0; it < 16; ++it) {
        size_t i = ((size_t)chunk * 16 + it) * 2048 + tid * 8;
        float4 v0 = *(const float4*)(x + i);
        float4 v1 = *(const float4*)(x + i + 4);
        union { bf16 h[8]; int4 v; } u;
        u.h[0] = __float2bfloat16(v0.x); u.h[1] = __float2bfloat16(v0.y);
        u.h[2] = __float2bfloat16(v0.z); u.h[3] = __float2bfloat16(v0.w);
        u.h[4] = __float2bfloat16(v1.x); u.h[5] = __float2bfloat16(v1.y);
        u.h[6] = __float2bfloat16(v1.z); u.h[7] = __float2bfloat16(v1.w);
        *(int4*)(x_bf + i) = u.v;
    }
}

// ---------------------------------------------------------------------------
// prep1: butterfly_wout [0,2048) || transpose_cvt [2048,6144) || cvt [6144,6400)
// ---------------------------------------------------------------------------
__global__ __launch_bounds__(256) void prep1(const float* __restrict__ w_out,
                                             const float* __restrict__ a_pad,
                                             const float* __restrict__ b_pad,
                                             const float* __restrict__ w_in,
                                             bf16* __restrict__ woutb,
                                             bf16* __restrict__ wint,
                                             const float* __restrict__ x,
                                             bf16* __restrict__ x_bf) {
    __shared__ float v[BDIM];
    __shared__ float tile[32][33];
    const int t = threadIdx.x;
    if (blockIdx.x < 2048) {
        const int o = blockIdx.x;
        const float* row = w_out + (size_t)o * BDIM;
        for (int i = t; i < BDIM / 4; i += 256)
            ((float4*)v)[i] = ((const float4*)row)[i];
        __syncthreads();
        for (int l = LOG_DIM - 1; l >= 0; --l) {
            #pragma unroll
            for (int pp = 0; pp < 4; ++pp) {
                int p = t + pp * 256;
                int j = p >> l;
                int s = p & ((1 << l) - 1);
                int i0 = (j << (l + 1)) | s;
                int i1 = i0 + (1 << l);
                float a = a_pad[l * (BDIM / 2) + j];
                float b = b_pad[l * (BDIM / 2) + j];
                float x0 = v[i0], x1 = v[i1];
                v[i0] = a * x0 - b * x1;
                v[i1] = b * x0 + a * x1;
            }
            __syncthreads();
        }
        union { bf16 h[8]; int4 vv; } u;
        #pragma unroll
        for (int j = 0; j < 8; ++j) u.h[j] = __float2bfloat16(v[t * 8 + j]);
        *(int4*)(woutb + (size_t)o * BDIM + t * 8) = u.vv;
    } else if (blockIdx.x < 6144) {
        const int b = blockIdx.x - 2048;
        const int bx = b & 63, by = b >> 6;
        const int tx = t & 31, ty = t >> 5;
        #pragma unroll
        for (int r = ty; r < 32; r += 8)
            tile[r][tx] = w_in[(size_t)(by * 32 + r) * NFEAT + bx * 32 + tx];
        __syncthreads();
        #pragma unroll
        for (int r = ty; r < 32; r += 8)
            wint[(size_t)(bx * 32 + r) * NFEAT + by * 32 + tx] = __float2bfloat16(tile[tx][r]);
    } else {
        cvt_chunk(x, x_bf, 768 + (blockIdx.x - 6144), t);
    }
}

// ---------------------------------------------------------------------------
// prep2: splitk M-GEMM [0,1024) || x cvt chunks [1024,1792)
// ---------------------------------------------------------------------------
__global__ __launch_bounds__(256, 2) void prep2(const bf16* __restrict__ Aw,
                                                const bf16* __restrict__ Btw,
                                                bf16* __restrict__ Cpart,
                                                const float* __restrict__ x,
                                                bf16* __restrict__ x_bf) {
    __shared__ bf16 sA[128 * 32];
    __shared__ bf16 sB[128 * 32];
    const int tid = threadIdx.x;

    if (blockIdx.x >= 1024) {
        cvt_chunk(x, x_bf, blockIdx.x - 1024, tid);
        return;
    }

    constexpr int BK = 32, LDA = 2048, KLEN = 512, NN = 2048;
    const int sk = blockIdx.x;
    const int bx = sk & 15, by = (sk >> 4) & 15, kz = sk >> 8;
    const bf16* A = Aw + kz * KLEN;
    const bf16* Bt = Btw + kz * KLEN;
    bf16* C = Cpart + (size_t)kz * NN * NN;

    const int wave = tid >> 6, lane = tid & 63;
    const int wr = wave >> 1, wc = wave & 1;
    const int mBase = by * 128, nBase = bx * 128;

    const int r0 = tid >> 2, c0 = tid & 3;
    const int r1 = (256 + tid) >> 2;

    const bf16* gA0 = A + (size_t)(mBase + r0) * LDA + c0 * 8;
    const bf16* gA1 = A + (size_t)(mBase + r1) * LDA + c0 * 8;
    const bf16* gB0 = Bt + (size_t)(nBase + r0) * LDA + c0 * 8;
    const bf16* gB1 = Bt + (size_t)(nBase + r1) * LDA + c0 * 8;

    char* lA0 = (char*)sA + (wave * 64) * 16;
    char* lA1 = (char*)sA + (256 + wave * 64) * 16;
    char* lB0 = (char*)sB + (wave * 64) * 16;
    char* lB1 = (char*)sB + (256 + wave * 64) * 16;

    f32x4 acc[4][4];
    #pragma unroll
    for (int i = 0; i < 4; ++i)
        #pragma unroll
        for (int j = 0; j < 4; ++j) acc[i][j] = (f32x4){0.f, 0.f, 0.f, 0.f};

    const int aRow = wr * 64 + (lane & 15);
    const int bRow = wc * 64 + (lane & 15);
    const int kOff = (lane >> 4) * 8;

    for (int k0 = 0; k0 < KLEN; k0 += BK) {
        LOAD_LDS16(gA0, lA0);
        LOAD_LDS16(gA1, lA1);
        LOAD_LDS16(gB0, lB0);
        LOAD_LDS16(gB1, lB1);
        gA0 += BK; gA1 += BK; gB0 += BK; gB1 += BK;
        __syncthreads();
        bf16x8 af[4], bfr[4];
        #pragma unroll
        for (int mf = 0; mf < 4; ++mf)
            af[mf] = *reinterpret_cast<const bf16x8*>(&sA[(aRow + mf * 16) * BK + kOff]);
        #pragma unroll
        for (int nf = 0; nf < 4; ++nf)
            bfr[nf] = *reinterpret_cast<const bf16x8*>(&sB[(bRow + nf * 16) * BK + kOff]);
        #pragma unroll
        for (int mf = 0; mf < 4; ++mf)
            #pragma unroll
            for (int nf = 0; nf < 4; ++nf)
                acc[mf][nf] = __builtin_amdgcn_mfma_f32_16x16x32_bf16(
                    af[mf], bfr[nf], acc[mf][nf], 0, 0, 0);
        __syncthreads();
    }

    const int cRow0 = mBase + wr * 64 + (lane >> 4) * 4;
    const int cCol0 = nBase + wc * 64 + (lane & 15);
    #pragma unroll
    for (int mf = 0; mf < 4; ++mf)
        #pragma unroll
        for (int nf = 0; nf < 4; ++nf)
            #pragma unroll
            for (int r = 0; r < 4; ++r)
                C[(size_t)(cRow0 + mf * 16 + r) * NN + cCol0 + nf * 16] =
                    __float2bfloat16(acc[mf][nf][r]);
}

// ---------------------------------------------------------------------------
// add four bf16 partials -> bf16
// ---------------------------------------------------------------------------
__global__ __launch_bounds__(256) void addcvt4(const bf16* __restrict__ p,
                                               bf16* __restrict__ out) {
    size_t i = ((size_t)blockIdx.x * 256 + threadIdx.x) * 8;
    constexpr size_t STRIDE = (size_t)2048 * 2048;
    float s[8];
    #pragma unroll
    for (int j = 0; j < 8; ++j) s[j] = 0.f;
    #pragma unroll
    for (int z = 0; z < 4; ++z) {
        union { bf16 h[8]; int4 v; } a;
        a.v = *(const int4*)(p + z * STRIDE + i);
        #pragma unroll
        for (int j = 0; j < 8; ++j) s[j] += __bfloat162float(a.h[j]);
    }
    union { bf16 h[8]; int4 v; } o;
    #pragma unroll
    for (int j = 0; j < 8; ++j) o.h[j] = __float2bfloat16(s[j]);
    *(int4*)(out + i) = o.v;
}

// ---------------------------------------------------------------------------
// Main GEMM (r4 exact: 256x256 tile, BK=64, 8-phase, T1..T5 + 1-phase-deep
//   register prefetch).  Best-known: 140 µs, MfmaUtil 42.6%, 0 conflicts.
//   ds_reads for phase p+1 issued after barrier#1(p), before MFMA(p);
//   slot-crossing prefetches sit after that phase's vmcnt(6)+barrier.
//   Swizzle: phys kc-chunk = kc ^ ((row>>1)&3), both sides (r3-verified).
// ---------------------------------------------------------------------------
#define GK 2048
#define LDS_SLOT 65536
#define LDS_BOFF 32768
#define LDS_KH 16384

__global__ __launch_bounds__(512, 2) void gemm256(const bf16* __restrict__ A,
                                                  const bf16* __restrict__ Bt,
                                                  const float* __restrict__ bias,
                                                  float* __restrict__ C) {
    __shared__ __align__(16) char lds[131072];

    const int tid = threadIdx.x;
    const int wave = tid >> 6, lane = tid & 63;
    const int l15 = lane & 15, kc = lane >> 4;
    const int wm = wave >> 2, wn = wave & 3;

    // T1: bijective XCD swizzle (512 wgs, 512%8==0)
    const int bid = blockIdx.x;
    const int swz = (bid & 7) * 64 + (bid >> 3);
    const int bm = swz >> 3, bn = swz & 7;
    const int mBase = bm * 256, nBase = bn * 256;

    // stage source (pre-swizzled): phys chunk tid -> logical chunk tid^((tid>>3)&3)
    const int c_log = tid ^ ((tid >> 3) & 3);
    const int srow = c_log >> 2, skc = c_log & 3;
    const bf16* gA = A + (size_t)(mBase + srow) * GK + skc * 8;
    const bf16* gB = Bt + (size_t)(nBase + srow) * GK + skc * 8;
    const int stgBase = wave * 1024;

    // read offsets: kcx = kc ^ ((l15>>1)&3)
    const int kcx = kc ^ ((l15 >> 1) & 3);
    const int aoff = wm * 8192 + l15 * 64 + kcx * 16;
    const int boff = LDS_BOFF + wn * 4096 + l15 * 64 + kcx * 16;

    f32x4 acc[8][4];
    #pragma unroll
    for (int i = 0; i < 8; ++i)
        #pragma unroll
        for (int j = 0; j < 4; ++j) acc[i][j] = (f32x4){0.f, 0.f, 0.f, 0.f};

    bf16x8 Aa[4], Ab[4], Ba[4], Bb[4];

#define STG(GSRC, LDSC, KT, KH) do {                                        \
    const bf16* _g = (GSRC) + (KT) * 64 + (KH) * 32;                        \
    LOAD_LDS16(_g, lds + (LDSC) + stgBase);                                 \
    LOAD_LDS16(_g + (size_t)128 * GK, lds + (LDSC) + stgBase + 8192);       \
} while (0)

#define READP(AN, BN, SLOT, KH, MH, DOB) do {                               \
    const int _rb = (SLOT) * LDS_SLOT + (KH) * LDS_KH;                      \
    _Pragma("unroll")                                                       \
    for (int _f = 0; _f < 4; ++_f)                                          \
        AN[_f] = *(const bf16x8*)(lds + _rb + aoff + (MH) * 4096 + _f * 1024); \
    if (DOB) {                                                              \
        _Pragma("unroll")                                                   \
        for (int _f = 0; _f < 4; ++_f)                                      \
            BN[_f] = *(const bf16x8*)(lds + _rb + boff + _f * 1024);        \
    }                                                                       \
} while (0)

    // prologue: slot0 complete (tile 0), then 3 regions of slot1 (tile 1)
    STG(gA, 0 * LDS_SLOT + 0, 0, 0);
    STG(gB, 0 * LDS_SLOT + LDS_BOFF + 0, 0, 0);
    STG(gA, 0 * LDS_SLOT + LDS_KH, 0, 1);
    STG(gB, 0 * LDS_SLOT + LDS_BOFF + LDS_KH, 0, 1);
    STG(gA, 1 * LDS_SLOT + 0, 1, 0);
    STG(gB, 1 * LDS_SLOT + LDS_BOFF + 0, 1, 0);
    STG(gB, 1 * LDS_SLOT + LDS_BOFF + LDS_KH, 1, 1);
    asm volatile("s_waitcnt vmcnt(6)");   // slot0's 8 loads landed
    __builtin_amdgcn_s_barrier();
    READP(Aa, Ba, 0, 0, 0, 1);            // regs for phase 0

    // PH: compute (MH) from CURA/CURB; prefetch (RS,RKH,RMH) into NXTA/NXTB;
    //     stage one freed region; vmcnt(6) only at p3/p7 (before barrier#1).
#define PH(CURA, CURB, NXTA, NXTB, MH, RS, RKH, RMH, RDOB, SGSRC, SLDS, SKT, SKH, DOVM) do { \
    STG(SGSRC, SLDS, SKT, SKH);                                             \
    if (DOVM) asm volatile("s_waitcnt vmcnt(6)");                           \
    __builtin_amdgcn_s_barrier();                                           \
    READP(NXTA, NXTB, RS, RKH, RMH, RDOB);                                  \
    __builtin_amdgcn_s_setprio(1);                                          \
    _Pragma("unroll")                                                       \
    for (int _mf = 0; _mf < 4; ++_mf)                                       \
        _Pragma("unroll")                                                   \
        for (int _nf = 0; _nf < 4; ++_nf)                                   \
            acc[(MH) * 4 + _mf][_nf] = __builtin_amdgcn_mfma_f32_16x16x32_bf16( \
                CURA[_mf], CURB[_nf], acc[(MH) * 4 + _mf][_nf], 0, 0, 0);   \
    __builtin_amdgcn_s_setprio(0);                                          \
    __builtin_amdgcn_s_barrier();                                           \
} while (0)

    // 32 K-tiles, 2 per iteration; ledger identical to round-3 (verified),
    // prefetch = next phase's compute coords. B sets: Ba p0-1, Bb p2-3,
    // Ba p4-5, Bb p6-7, wrap -> Ba (consistent).
    for (int it = 0; it < 16; ++it) {
        const int t0 = 2 * it;
        const int t1 = (t0 + 1) & 31, t2 = (t0 + 2) & 31, t3 = (t0 + 3) & 31;
        PH(Aa, Ba, Ab, Bb, 0, 0, 0, 1, 0, gA, 1 * LDS_SLOT + LDS_KH,            t1, 1, 0);
        PH(Ab, Ba, Aa, Bb, 1, 0, 1, 0, 1, gB, 0 * LDS_SLOT + LDS_BOFF,          t2, 0, 0);
        PH(Aa, Bb, Ab, Ba, 0, 0, 1, 1, 0, gA, 0 * LDS_SLOT + 0,                 t2, 0, 0);
        PH(Ab, Bb, Aa, Ba, 1, 1, 0, 0, 1, gB, 0 * LDS_SLOT + LDS_BOFF + LDS_KH, t2, 1, 1);
        PH(Aa, Ba, Ab, Bb, 0, 1, 0, 1, 0, gA, 0 * LDS_SLOT + LDS_KH,            t2, 1, 0);
        PH(Ab, Ba, Aa, Bb, 1, 1, 1, 0, 1, gB, 1 * LDS_SLOT + LDS_BOFF,          t3, 0, 0);
        PH(Aa, Bb, Ab, Ba, 0, 1, 1, 1, 0, gA, 1 * LDS_SLOT + 0,                 t3, 0, 0);
        PH(Ab, Bb, Aa, Ba, 1, 0, 0, 0, 1, gB, 1 * LDS_SLOT + LDS_BOFF + LDS_KH, t3, 1, 1);
    }

    // epilogue: C/D layout col=lane&15, row=(lane>>4)*4+reg
    const int cRow0 = mBase + wm * 128 + (lane >> 4) * 4;
    const int cCol0 = nBase + wn * 64 + l15;
    float bv[4];
    #pragma unroll
    for (int nf = 0; nf < 4; ++nf) bv[nf] = bias[cCol0 + nf * 16];
    #pragma unroll
    for (int Mf = 0; Mf < 8; ++Mf)
        #pragma unroll
        for (int nf = 0; nf < 4; ++nf)
            #pragma unroll
            for (int r = 0; r < 4; ++r)
                C[(size_t)(cRow0 + Mf * 16 + r) * GK + cCol0 + nf * 16] =
                    acc[Mf][nf][r] + bv[nf];
#undef PH
#undef READP
#undef STG
}

// ---------------------------------------------------------------------------
// launch
// ---------------------------------------------------------------------------
extern "C" void kernel_launch(void* const* d_in, const int* in_sizes, int n_in,
                              void* d_out, int out_size, void* d_ws, size_t ws_size,
                              hipStream_t stream) {
    const float* x     = (const float*)d_in[0];
    const float* w_in  = (const float*)d_in[1];
    const float* w_out = (const float*)d_in[2];
    const float* b_out = (const float*)d_in[3];
    const float* a_pad = (const float*)d_in[4];
    const float* b_pad = (const float*)d_in[5];
    float* out = (float*)d_out;

    char* ws = (char*)d_ws;
    bf16* x_bf  = (bf16*)ws;                        // 67,108,864 B
    bf16* woutb = (bf16*)(ws + (size_t)67108864);   //  8,388,608 B
    bf16* wint  = (bf16*)(ws + (size_t)75497472);   //  8,388,608 B
    bf16* mcomb = (bf16*)(ws + (size_t)83886080);   //  8,388,608 B  (ws total 92 MB)

    // split-K partials live in d_out (134 MB, fully overwritten by gemm256)
    bf16* part = (bf16*)d_out;                      // 4 x 8 MB

    // prep1: butterfly(W_out) || transpose(W_in) || 25% of x-cvt
    prep1<<<dim3(6400), dim3(256), 0, stream>>>(w_out, a_pad, b_pad, w_in,
                                                woutb, wint, x, x_bf);
    // prep2: splitk M-GEMM [0,1024) || 75% of x-cvt [1024,1792)
    prep2<<<dim3(1792), dim3(256), 0, stream>>>(woutb, wint, part, x, x_bf);
    addcvt4<<<dim3(NFEAT * BDIM / (256 * 8)), dim3(256), 0, stream>>>(part, mcomb);
    // out = x @ M^T + b  (8-phase 256^2 + reg prefetch)
    gemm256<<<dim3((BATCH / 256) * (NFEAT / 256)), dim3(512), 0, stream>>>(
        x_bf, mcomb, b_out, out);
}